// Round 20
// baseline (170.742 us; speedup 1.0000x reference)
//
#include <hip/hip_runtime.h>

// B=256, T=5, S=64, F=256, H=4, Fh=64, N=H*B=1024, M=81920 rows of [.,256]

typedef unsigned short ushort_t;
typedef __attribute__((ext_vector_type(8))) short bf16x8;
typedef __attribute__((ext_vector_type(4))) float f32x4;

__device__ inline ushort_t f2bf(float f) {            // RNE f32 -> bf16
  unsigned u = __float_as_uint(f);
  return (ushort_t)((u + 0x7FFFu + ((u >> 16) & 1u)) >> 16);
}
__device__ inline float bflo(unsigned u) { return __uint_as_float(u << 16); }
__device__ inline float bfhi(unsigned u) { return __uint_as_float(u & 0xFFFF0000u); }
__device__ inline uint4 pack8(float4 a, float4 b) {   // 8 f32 -> 8 bf16 in uint4
  uint4 r;
  r.x = (unsigned)f2bf(a.x) | ((unsigned)f2bf(a.y) << 16);
  r.y = (unsigned)f2bf(a.z) | ((unsigned)f2bf(a.w) << 16);
  r.z = (unsigned)f2bf(b.x) | ((unsigned)f2bf(b.y) << 16);
  r.w = (unsigned)f2bf(b.z) | ((unsigned)f2bf(b.w) << 16);
  return r;
}
// async global->LDS, 16B per lane; LDS dest = wave-uniform base + lane*16
__device__ inline void gload16(const ushort_t* g, ushort_t* l) {
  __builtin_amdgcn_global_load_lds((const __attribute__((address_space(1))) void*)g,
                                   (__attribute__((address_space(3))) void*)l, 16, 0, 0);
}

// ---------------- fused prep: convert_w | prior | bias_prior_sum | k/xb -----------
__global__ __launch_bounds__(256, 4) void prep_kernel(
    const float* __restrict__ x, const float* __restrict__ u,
    const float* __restrict__ Wq, const float* __restrict__ Wv,
    const float* __restrict__ Wo, const float* __restrict__ dis,
    const float* __restrict__ sigma, const float* __restrict__ bias,
    ushort_t* __restrict__ Wt, float* __restrict__ prior,
    float* __restrict__ bps, ushort_t* __restrict__ kout,
    ushort_t* __restrict__ xb) {
  __shared__ float red[4][64];
  const int blk = blockIdx.x, tid = threadIdx.x;
  if (blk < 768) {
    int id = blk * 256 + tid;                  // 196608
    int mat = id >> 16, rem = id & 65535;
    int n = rem >> 8, k = rem & 255;
    const float* W = mat == 0 ? Wq : (mat == 1 ? Wv : Wo);
    Wt[id] = f2bf(W[k * 256 + n]);
  } else if (blk < 848) {
    int i = (blk - 768) * 256 + tid;           // 20480
    int ts = i >> 6;
    float sg = sigma[ts];
    float d = dis[i];
    prior[i] = 0.3989422804014327f / sg * __expf(-d * d / (2.f * sg * sg));
  } else if (blk < 2128) {
    int b2 = blk - 848;                        // nb*5 + t, 1280 blocks
    int t = b2 % 5;
    const float* bp = bias + (size_t)b2 * 4096;
    int c = tid & 63, sg_ = tid >> 6;
    float sum = 0.f;
    for (int s = sg_ * 16; s < sg_ * 16 + 16; ++s) {
      float sgm = sigma[t * 64 + s];
      float d = dis[t * 4096 + s * 64 + c];
      float pr = 0.3989422804014327f / sgm * __expf(-d * d / (2.f * sgm * sgm));
      sum += bp[s * 64 + c] * pr;
    }
    red[sg_][c] = sum;
    __syncthreads();
    if (tid < 64)
      bps[(size_t)b2 * 64 + tid] = red[0][tid] + red[1][tid] + red[2][tid] + red[3][tid];
  } else {
    int i = (blk - 2128) * 256 + tid;          // 8-float id, 524288 total
    size_t j = (size_t)i * 8;
    int b = (int)(j >> 14);
    int off = (int)(j & 16383);
    const float* xp = x + (size_t)b * 81920 + off;
    ushort_t* xq = xb + (size_t)b * 81920 + off;
    float u0 = u[0], u1 = u[1], u2 = u[2], u3 = u[3], u4 = u[4];
    float4 lo[5], hi[5];
#pragma unroll
    for (int t = 0; t < 5; ++t) {
      lo[t] = *(const float4*)(xp + t * 16384);
      hi[t] = *(const float4*)(xp + t * 16384 + 4);
    }
#pragma unroll
    for (int t = 0; t < 5; ++t)
      *(uint4*)(xq + t * 16384) = pack8(lo[t], hi[t]);
    float4 rl, rh;
    rl.x = u0*lo[0].x + u1*lo[1].x + u2*lo[2].x + u3*lo[3].x + u4*lo[4].x;
    rl.y = u0*lo[0].y + u1*lo[1].y + u2*lo[2].y + u3*lo[3].y + u4*lo[4].y;
    rl.z = u0*lo[0].z + u1*lo[1].z + u2*lo[2].z + u3*lo[3].z + u4*lo[4].z;
    rl.w = u0*lo[0].w + u1*lo[1].w + u2*lo[2].w + u3*lo[3].w + u4*lo[4].w;
    rh.x = u0*hi[0].x + u1*hi[1].x + u2*hi[2].x + u3*hi[3].x + u4*hi[4].x;
    rh.y = u0*hi[0].y + u1*hi[1].y + u2*hi[2].y + u3*hi[3].y + u4*hi[4].y;
    rh.z = u0*hi[0].z + u1*hi[1].z + u2*hi[2].z + u3*hi[3].z + u4*hi[4].z;
    rh.w = u0*hi[0].w + u1*hi[1].w + u2*hi[2].w + u3*hi[3].w + u4*hi[4].w;
    *(uint4*)(kout + j) = pack8(rl, rh);
  }
}

// ---------------- fused q-GEMM + score (LDS-staged) -------------------------------
__global__ __launch_bounds__(256) void qscore(const ushort_t* __restrict__ xb,
                                              const ushort_t* __restrict__ Wtq,
                                              const ushort_t* __restrict__ kbuf,
                                              const float* __restrict__ prior,
                                              const float* __restrict__ bps,
                                              float* __restrict__ ssum) {
  __shared__ __align__(16) char smem[46080];           // union: As+Bs (43K) | qlds (45K)
  ushort_t* As_ = (ushort_t*)smem;                     // [80*64]
  ushort_t* Bs_ = (ushort_t*)(smem + 10240);           // [256*64]
  ushort_t* qlds = (ushort_t*)smem;                    // [5*64*72]
  const int n = blockIdx.x;
  const int tid = threadIdx.x;
  const int lane = tid & 63, w = tid >> 6;
  const int cl = lane & 15, ql = lane >> 4, l7 = lane & 7;
  const ushort_t* A = xb + (size_t)n * 20480;          // 80 rows x 256

  const int c = w * 16 + cl;
  const int nb = n & 255;
  const ushort_t* kbp = kbuf + (size_t)(n >> 2) * 16384 + (n & 3) * 64;
  bf16x8 kfr0 = *(const bf16x8*)(kbp + c * 256 + ql * 8);
  bf16x8 kfr1 = *(const bf16x8*)(kbp + c * 256 + ql * 8 + 32);

  f32x4 acc[5][4];
#pragma unroll
  for (int mi = 0; mi < 5; ++mi)
#pragma unroll
    for (int ni = 0; ni < 4; ++ni) acc[mi][ni] = (f32x4){0.f, 0.f, 0.f, 0.f};

  for (int t4 = 0; t4 < 4; ++t4) {
    const int k0 = t4 * 64;
    if (t4) __syncthreads();
#pragma unroll
    for (int l = 0; l < 3; ++l) {              // A: 640 16B chunks
      int i = l * 256 + tid;
      if (i < 640) {
        int r = i >> 3, cc = i & 7;
        uint4 v = *(const uint4*)(A + (size_t)r * 256 + k0 + cc * 8);
        *(uint4*)&As_[r * 64 + ((cc ^ (r & 7)) * 8)] = v;
      }
    }
#pragma unroll
    for (int l = 0; l < 8; ++l) {              // B: 2048 16B chunks
      int i = l * 256 + tid;
      int nn = i >> 3, cc = i & 7;
      uint4 v = *(const uint4*)(Wtq + (size_t)nn * 256 + k0 + cc * 8);
      *(uint4*)&Bs_[nn * 64 + ((cc ^ (nn & 7)) * 8)] = v;
    }
    __syncthreads();
#pragma unroll
    for (int kk = 0; kk < 2; ++kk) {
      const int offk = (((kk << 2) | ql) ^ l7) * 8;
      bf16x8 bfr[4];
#pragma unroll
      for (int ni = 0; ni < 4; ++ni)
        bfr[ni] = *(const bf16x8*)&Bs_[(w * 64 + ni * 16 + cl) * 64 + offk];
#pragma unroll
      for (int mi = 0; mi < 5; ++mi) {
        bf16x8 afr = *(const bf16x8*)&As_[(mi * 16 + cl) * 64 + offk];
#pragma unroll
        for (int ni = 0; ni < 4; ++ni)
          acc[mi][ni] = __builtin_amdgcn_mfma_f32_16x16x32_bf16(afr, bfr[ni], acc[mi][ni], 0, 0, 0);
      }
    }
  }
  __syncthreads();                             // staging reads done; reuse smem as qlds
#pragma unroll
  for (int mi = 0; mi < 5; ++mi)
#pragma unroll
    for (int ni = 0; ni < 4; ++ni)
#pragma unroll
      for (int rr = 0; rr < 4; ++rr)
        qlds[(mi * 64 + 16 * ql + 4 * rr + w) * 72 + ni * 16 + cl] = f2bf(acc[mi][ni][rr]);
  __syncthreads();

#pragma unroll
  for (int t = 0; t < 5; ++t) {
    f32x4 sacc[4];
#pragma unroll
    for (int si = 0; si < 4; ++si) {
      bf16x8 a0 = *(const bf16x8*)&qlds[(t * 64 + si * 16 + cl) * 72 + ql * 8];
      bf16x8 a1 = *(const bf16x8*)&qlds[(t * 64 + si * 16 + cl) * 72 + ql * 8 + 32];
      f32x4 z = (f32x4){0.f, 0.f, 0.f, 0.f};
      z = __builtin_amdgcn_mfma_f32_16x16x32_bf16(a0, kfr0, z, 0, 0, 0);
      z = __builtin_amdgcn_mfma_f32_16x16x32_bf16(a1, kfr1, z, 0, 0, 0);
      sacc[si] = z;
    }
    const float* pp = prior + t * 4096;
    float colsum = 0.f;
#pragma unroll
    for (int si = 0; si < 4; ++si) {
#pragma unroll
      for (int r = 0; r < 4; ++r) {
        int s = si * 16 + ql * 4 + r;
        float sg = 1.f / (1.f + __expf(-sacc[si][r] * 0.125f));
        colsum += sg * pp[s * 64 + c];
      }
    }
    colsum += __shfl_xor(colsum, 16);
    colsum += __shfl_xor(colsum, 32);
    if (ql == 0)
      ssum[(size_t)n * 320 + t * 64 + c] = colsum - bps[((size_t)nb * 5 + t) * 64 + c];
  }
}

// ---------------- fused v-GEMM + o-GEMM + SE + final (one block per b) ------------
// 256 blocks x 512 thr (8 waves, 2 rows x 4 cols). For tg=0..4 (bt group g=b*5+tg,
// rows [g*64,g*64+64)): phase1 V=xb@Wv^T (staged, source-XOR swizzle), scale by
// ssum, bf16 -> Vs (chunk-XOR); phase2 O=Vs@Wo^T; epilogue ob write + avg/max into
// LDS seAvg/seMax[tg]. Then thread0 computes se[0..4] LOCALLY (all 5 groups of b
// are block-local), broadcast, and a residual pass reads ob/xb (L2-hot) and
// writes out = bf16(o)*se + bf16(x). Numerics identical to the split pipeline.
__global__ __launch_bounds__(512, 2) void vof_gemm(
    const ushort_t* __restrict__ xb, const ushort_t* __restrict__ Wtv,
    const ushort_t* __restrict__ Wto, const float* __restrict__ ssum,
    ushort_t* __restrict__ ob, const float* __restrict__ fc1w,
    const float* __restrict__ fc1b, const float* __restrict__ fc2w,
    const float* __restrict__ fc2b, const float* __restrict__ bili,
    float* __restrict__ out) {
  __shared__ __align__(16) ushort_t As_[64 * 64];      // 8K
  __shared__ __align__(16) ushort_t Bs_[256 * 64];     // 32K
  __shared__ __align__(16) ushort_t Vs_[64 * 256];     // 32K
  __shared__ float redS[8], redM[8];
  __shared__ float seAvg[5], seMax[5], seBC[5];
  const int tid = threadIdx.x;
  const int lane = tid & 63;
  const int w = tid >> 6, wr = w >> 2, wc = w & 3;
  const int b = blockIdx.x;                            // 256 blocks
  const int cl = lane & 15, ql = lane >> 4, l7 = lane & 7;

  for (int tg = 0; tg < 5; ++tg) {
    const int row0 = b * 320 + tg * 64;
    f32x4 acc[2][4];
#pragma unroll
    for (int mi = 0; mi < 2; ++mi)
#pragma unroll
      for (int ni = 0; ni < 4; ++ni) acc[mi][ni] = (f32x4){0.f, 0.f, 0.f, 0.f};

    // ---- phase 1: V = xb @ Wv^T ----
    for (int t = 0; t < 4; ++t) {
      const int k0 = t * 64;
      if (t || tg) __syncthreads();
      {                                        // A: 512 chunks, 1/thread
        int i = tid;
        int r = i >> 3, cpos = i & 7, csrc = cpos ^ (r & 7);
        gload16(xb + (size_t)(row0 + r) * 256 + k0 + csrc * 8, &As_[(w * 64) * 8]);
      }
#pragma unroll
      for (int l = 0; l < 4; ++l) {            // B: 2048 chunks (Wv)
        int i = l * 512 + tid;
        int n = i >> 3, cpos = i & 7, csrc = cpos ^ (n & 7);
        gload16(Wtv + (size_t)n * 256 + k0 + csrc * 8, &Bs_[(l * 512 + w * 64) * 8]);
      }
      __syncthreads();
#pragma unroll
      for (int kk = 0; kk < 2; ++kk) {
        const int offk = (((kk << 2) | ql) ^ l7) * 8;
        bf16x8 bfr[4], afr[2];
#pragma unroll
        for (int ni = 0; ni < 4; ++ni)
          bfr[ni] = *(const bf16x8*)&Bs_[(wc * 64 + ni * 16 + cl) * 64 + offk];
#pragma unroll
        for (int mi = 0; mi < 2; ++mi)
          afr[mi] = *(const bf16x8*)&As_[(wr * 32 + mi * 16 + cl) * 64 + offk];
#pragma unroll
        for (int mi = 0; mi < 2; ++mi)
#pragma unroll
          for (int ni = 0; ni < 4; ++ni)
            acc[mi][ni] = __builtin_amdgcn_mfma_f32_16x16x32_bf16(afr[mi], bfr[ni], acc[mi][ni], 0, 0, 0);
      }
    }
    // scale + write Vs (chunk-XOR swizzled)
#pragma unroll
    for (int mi = 0; mi < 2; ++mi) {
      float sc[4];
#pragma unroll
      for (int r = 0; r < 4; ++r)
        sc[r] = ssum[(size_t)(row0 + wr * 32 + mi * 16 + ql * 4 + r) * 4 + wc];
#pragma unroll
      for (int ni = 0; ni < 4; ++ni) {
        int col = wc * 64 + ni * 16 + cl;
#pragma unroll
        for (int r = 0; r < 4; ++r) {
          int row = wr * 32 + mi * 16 + ql * 4 + r;
          int ch = (col >> 3) ^ (row & 31);
          Vs_[row * 256 + ch * 8 + (col & 7)] = f2bf(acc[mi][ni][r] * sc[r]);
        }
      }
    }
    __syncthreads();                           // Vs visible; phase-1 Bs reads done

    // ---- phase 2: O = Vs @ Wo^T ----
#pragma unroll
    for (int mi = 0; mi < 2; ++mi)
#pragma unroll
      for (int ni = 0; ni < 4; ++ni) acc[mi][ni] = (f32x4){0.f, 0.f, 0.f, 0.f};
    for (int t = 0; t < 4; ++t) {
      const int k0 = t * 64;
      if (t) __syncthreads();
#pragma unroll
      for (int l = 0; l < 4; ++l) {            // B: 2048 chunks (Wo)
        int i = l * 512 + tid;
        int n = i >> 3, cpos = i & 7, csrc = cpos ^ (n & 7);
        gload16(Wto + (size_t)n * 256 + k0 + csrc * 8, &Bs_[(l * 512 + w * 64) * 8]);
      }
      __syncthreads();
#pragma unroll
      for (int kk = 0; kk < 2; ++kk) {
        const int offk = (((kk << 2) | ql) ^ l7) * 8;
        const int ch = t * 8 + kk * 4 + ql;
        bf16x8 bfr[4], afr[2];
#pragma unroll
        for (int ni = 0; ni < 4; ++ni)
          bfr[ni] = *(const bf16x8*)&Bs_[(wc * 64 + ni * 16 + cl) * 64 + offk];
#pragma unroll
        for (int mi = 0; mi < 2; ++mi) {
          int row = wr * 32 + mi * 16 + cl;
          afr[mi] = *(const bf16x8*)&Vs_[row * 256 + (ch ^ (row & 31)) * 8];
        }
#pragma unroll
        for (int mi = 0; mi < 2; ++mi)
#pragma unroll
          for (int ni = 0; ni < 4; ++ni)
            acc[mi][ni] = __builtin_amdgcn_mfma_f32_16x16x32_bf16(afr[mi], bfr[ni], acc[mi][ni], 0, 0, 0);
      }
    }
    // epilogue: write ob bf16 + avg/max for this tg
    float lsum = 0.f, lmax = -3.4e38f;
#pragma unroll
    for (int mi = 0; mi < 2; ++mi)
#pragma unroll
      for (int ni = 0; ni < 4; ++ni) {
        int col = wc * 64 + ni * 16 + cl;
#pragma unroll
        for (int r = 0; r < 4; ++r) {
          int row = row0 + wr * 32 + mi * 16 + ql * 4 + r;
          float f = acc[mi][ni][r];
          ob[(size_t)row * 256 + col] = f2bf(f);
          lsum += f; lmax = fmaxf(lmax, f);
        }
      }
#pragma unroll
    for (int off = 32; off; off >>= 1) {
      lsum += __shfl_xor(lsum, off);
      lmax = fmaxf(lmax, __shfl_xor(lmax, off));
    }
    if (lane == 0) { redS[w] = lsum; redM[w] = lmax; }
    __syncthreads();                           // redS/redM ready; phase-2 reads done
    if (tid == 0) {
      float s = 0.f, m = -3.4e38f;
#pragma unroll
      for (int i = 0; i < 8; ++i) { s += redS[i]; m = fmaxf(m, redM[i]); }
      seAvg[tg] = s * (1.f / 16384.f);
      seMax[tg] = m;
    }
    // (next iteration's leading __syncthreads protects redS reuse)
  }
  __syncthreads();                             // seAvg/seMax complete
  if (tid == 0) {                              // local SE MLP for this b
    float w_ = bili[0];
    float s12[2][5];
#pragma unroll
    for (int p = 0; p < 2; ++p) {
      const float* in = p == 0 ? seAvg : seMax;
      float h[25];
      for (int jj = 0; jj < 25; ++jj) {
        float hh = fc1b[jj];
        for (int tt = 0; tt < 5; ++tt) hh += in[tt] * fc1w[tt * 25 + jj];
        h[jj] = fmaxf(hh, 0.f);
      }
      for (int t = 0; t < 5; ++t) {
        float a = fc2b[t];
        for (int jj = 0; jj < 25; ++jj) a += h[jj] * fc2w[jj * 5 + t];
        s12[p][t] = 1.f / (1.f + __expf(-a));
      }
    }
    for (int t = 0; t < 5; ++t)
      seBC[t] = (1.f - w_) * s12[0][t] + w_ * s12[1][t];
  }
  __syncthreads();                             // se ready; ob stores drained (vmcnt 0)

  // residual pass: out = bf16(o)*se[t] + bf16(x), rows b*320..b*320+320
  for (int cch = 0; cch < 20; ++cch) {
    int chunk = cch * 512 + tid;               // 10240 chunks of 8 elems
    int e = chunk * 8;
    int row = e >> 8;                          // 0..319
    float s = seBC[row >> 6];
    size_t ge = (size_t)b * 81920 + e;
    uint4 uo = *(const uint4*)(ob + ge);
    uint4 ux = *(const uint4*)(xb + ge);
    float4 r0 = {bflo(uo.x) * s + bflo(ux.x), bfhi(uo.x) * s + bfhi(ux.x),
                 bflo(uo.y) * s + bflo(ux.y), bfhi(uo.y) * s + bfhi(ux.y)};
    float4 r1 = {bflo(uo.z) * s + bflo(ux.z), bfhi(uo.z) * s + bfhi(ux.z),
                 bflo(uo.w) * s + bflo(ux.w), bfhi(uo.w) * s + bfhi(ux.w)};
    *(float4*)(out + ge) = r0;
    *(float4*)(out + ge + 4) = r1;
  }
}

extern "C" void kernel_launch(void* const* d_in, const int* in_sizes, int n_in,
                              void* d_out, int out_size, void* d_ws, size_t ws_size,
                              hipStream_t stream) {
  const float* x     = (const float*)d_in[0];
  const float* bias  = (const float*)d_in[1];
  const float* Wq    = (const float*)d_in[2];
  const float* Wv    = (const float*)d_in[3];
  const float* Wo    = (const float*)d_in[4];
  const float* u_t   = (const float*)d_in[5];
  const float* dis   = (const float*)d_in[6];
  const float* sigma = (const float*)d_in[7];
  const float* fc1w  = (const float*)d_in[8];
  const float* fc1b  = (const float*)d_in[9];
  const float* fc2w  = (const float*)d_in[10];
  const float* fc2b  = (const float*)d_in[11];
  const float* bili  = (const float*)d_in[12];
  float* out = (float*)d_out;

  // workspace layout (bytes), ~94.5 MB
  char* wsb = (char*)d_ws;
  ushort_t* xbuf = (ushort_t*)wsb;             wsb += 41943040;  // bf16(x)
  ushort_t* obuf = (ushort_t*)wsb;             wsb += 41943040;  // o bf16 (L2-hot)
  ushort_t* kb   = (ushort_t*)wsb;             wsb += 8388608;   // k bf16 [B,S,F]
  ushort_t* Wt   = (ushort_t*)wsb;             wsb += 393216;    // 3 x W^T bf16
  float*    ssum = (float*)wsb;                wsb += 1310720;
  float*    prior= (float*)wsb;                wsb += 81920;
  float*    bps  = (float*)wsb;                wsb += 327680;

  // 1) fused prep: Wt | prior | bps | (k, xb)
  prep_kernel<<<4176, 256, 0, stream>>>(x, u_t, Wq, Wv, Wo, dis, sigma, bias,
                                        Wt, prior, bps, kb, xbuf);
  // 2) fused q-GEMM + score (q never touches HBM)
  qscore<<<1024, 256, 0, stream>>>(xbuf, Wt, kb, prior, bps, ssum);
  // 3) fused v-GEMM + o-GEMM + SE + residual (one block per b; no final kernel)
  vof_gemm<<<256, 512, 0, stream>>>(xbuf, Wt + 65536, Wt + 131072, ssum, obuf,
                                    fc1w, fc1b, fc2w, fc2b, bili, out);
}

// Round 21
// 144.699 us; speedup vs baseline: 1.1800x; 1.1800x over previous
//
#include <hip/hip_runtime.h>

// B=256, T=5, S=64, F=256, H=4, Fh=64, N=H*B=1024, M=81920 rows of [.,256]

typedef unsigned short ushort_t;
typedef __attribute__((ext_vector_type(8))) short bf16x8;
typedef __attribute__((ext_vector_type(4))) float f32x4;

__device__ inline ushort_t f2bf(float f) {            // RNE f32 -> bf16
  unsigned u = __float_as_uint(f);
  return (ushort_t)((u + 0x7FFFu + ((u >> 16) & 1u)) >> 16);
}
__device__ inline float bflo(unsigned u) { return __uint_as_float(u << 16); }
__device__ inline float bfhi(unsigned u) { return __uint_as_float(u & 0xFFFF0000u); }
__device__ inline uint4 pack8(float4 a, float4 b) {   // 8 f32 -> 8 bf16 in uint4
  uint4 r;
  r.x = (unsigned)f2bf(a.x) | ((unsigned)f2bf(a.y) << 16);
  r.y = (unsigned)f2bf(a.z) | ((unsigned)f2bf(a.w) << 16);
  r.z = (unsigned)f2bf(b.x) | ((unsigned)f2bf(b.y) << 16);
  r.w = (unsigned)f2bf(b.z) | ((unsigned)f2bf(b.w) << 16);
  return r;
}
// async global->LDS, 16B per lane; LDS dest = wave-uniform base + lane*16
__device__ inline void gload16(const ushort_t* g, ushort_t* l) {
  __builtin_amdgcn_global_load_lds((const __attribute__((address_space(1))) void*)g,
                                   (__attribute__((address_space(3))) void*)l, 16, 0, 0);
}

// ---------------- fused prep: convert_w | prior | bias_prior_sum | k/xb -----------
__global__ __launch_bounds__(256, 4) void prep_kernel(
    const float* __restrict__ x, const float* __restrict__ u,
    const float* __restrict__ Wq, const float* __restrict__ Wv,
    const float* __restrict__ Wo, const float* __restrict__ dis,
    const float* __restrict__ sigma, const float* __restrict__ bias,
    ushort_t* __restrict__ Wt, float* __restrict__ prior,
    float* __restrict__ bps, ushort_t* __restrict__ kout,
    ushort_t* __restrict__ xb) {
  __shared__ float red[4][64];
  const int blk = blockIdx.x, tid = threadIdx.x;
  if (blk < 768) {
    int id = blk * 256 + tid;                  // 196608
    int mat = id >> 16, rem = id & 65535;
    int n = rem >> 8, k = rem & 255;
    const float* W = mat == 0 ? Wq : (mat == 1 ? Wv : Wo);
    Wt[id] = f2bf(W[k * 256 + n]);
  } else if (blk < 848) {
    int i = (blk - 768) * 256 + tid;           // 20480
    int ts = i >> 6;
    float sg = sigma[ts];
    float d = dis[i];
    prior[i] = 0.3989422804014327f / sg * __expf(-d * d / (2.f * sg * sg));
  } else if (blk < 2128) {
    int b2 = blk - 848;                        // nb*5 + t, 1280 blocks
    int t = b2 % 5;
    const float* bp = bias + (size_t)b2 * 4096;
    int c = tid & 63, sg_ = tid >> 6;
    float sum = 0.f;
    for (int s = sg_ * 16; s < sg_ * 16 + 16; ++s) {
      float sgm = sigma[t * 64 + s];
      float d = dis[t * 4096 + s * 64 + c];
      float pr = 0.3989422804014327f / sgm * __expf(-d * d / (2.f * sgm * sgm));
      sum += bp[s * 64 + c] * pr;
    }
    red[sg_][c] = sum;
    __syncthreads();
    if (tid < 64)
      bps[(size_t)b2 * 64 + tid] = red[0][tid] + red[1][tid] + red[2][tid] + red[3][tid];
  } else {
    int i = (blk - 2128) * 256 + tid;          // 8-float id, 524288 total
    size_t j = (size_t)i * 8;
    int b = (int)(j >> 14);
    int off = (int)(j & 16383);
    const float* xp = x + (size_t)b * 81920 + off;
    ushort_t* xq = xb + (size_t)b * 81920 + off;
    float u0 = u[0], u1 = u[1], u2 = u[2], u3 = u[3], u4 = u[4];
    float4 lo[5], hi[5];
#pragma unroll
    for (int t = 0; t < 5; ++t) {
      lo[t] = *(const float4*)(xp + t * 16384);
      hi[t] = *(const float4*)(xp + t * 16384 + 4);
    }
#pragma unroll
    for (int t = 0; t < 5; ++t)
      *(uint4*)(xq + t * 16384) = pack8(lo[t], hi[t]);
    float4 rl, rh;
    rl.x = u0*lo[0].x + u1*lo[1].x + u2*lo[2].x + u3*lo[3].x + u4*lo[4].x;
    rl.y = u0*lo[0].y + u1*lo[1].y + u2*lo[2].y + u3*lo[3].y + u4*lo[4].y;
    rl.z = u0*lo[0].z + u1*lo[1].z + u2*lo[2].z + u3*lo[3].z + u4*lo[4].z;
    rl.w = u0*lo[0].w + u1*lo[1].w + u2*lo[2].w + u3*lo[3].w + u4*lo[4].w;
    rh.x = u0*hi[0].x + u1*hi[1].x + u2*hi[2].x + u3*hi[3].x + u4*hi[4].x;
    rh.y = u0*hi[0].y + u1*hi[1].y + u2*hi[2].y + u3*hi[3].y + u4*hi[4].y;
    rh.z = u0*hi[0].z + u1*hi[1].z + u2*hi[2].z + u3*hi[3].z + u4*hi[4].z;
    rh.w = u0*hi[0].w + u1*hi[1].w + u2*hi[2].w + u3*hi[3].w + u4*hi[4].w;
    *(uint4*)(kout + j) = pack8(rl, rh);
  }
}

// ---------------- fused q-GEMM + score (LDS-staged) -------------------------------
__global__ __launch_bounds__(256) void qscore(const ushort_t* __restrict__ xb,
                                              const ushort_t* __restrict__ Wtq,
                                              const ushort_t* __restrict__ kbuf,
                                              const float* __restrict__ prior,
                                              const float* __restrict__ bps,
                                              float* __restrict__ ssum) {
  __shared__ __align__(16) char smem[46080];           // union: As+Bs (43K) | qlds (45K)
  ushort_t* As_ = (ushort_t*)smem;                     // [80*64]
  ushort_t* Bs_ = (ushort_t*)(smem + 10240);           // [256*64]
  ushort_t* qlds = (ushort_t*)smem;                    // [5*64*72]
  const int n = blockIdx.x;
  const int tid = threadIdx.x;
  const int lane = tid & 63, w = tid >> 6;
  const int cl = lane & 15, ql = lane >> 4, l7 = lane & 7;
  const ushort_t* A = xb + (size_t)n * 20480;          // 80 rows x 256

  const int c = w * 16 + cl;
  const int nb = n & 255;
  const ushort_t* kbp = kbuf + (size_t)(n >> 2) * 16384 + (n & 3) * 64;
  bf16x8 kfr0 = *(const bf16x8*)(kbp + c * 256 + ql * 8);
  bf16x8 kfr1 = *(const bf16x8*)(kbp + c * 256 + ql * 8 + 32);

  f32x4 acc[5][4];
#pragma unroll
  for (int mi = 0; mi < 5; ++mi)
#pragma unroll
    for (int ni = 0; ni < 4; ++ni) acc[mi][ni] = (f32x4){0.f, 0.f, 0.f, 0.f};

  for (int t4 = 0; t4 < 4; ++t4) {
    const int k0 = t4 * 64;
    if (t4) __syncthreads();
#pragma unroll
    for (int l = 0; l < 3; ++l) {              // A: 640 16B chunks
      int i = l * 256 + tid;
      if (i < 640) {
        int r = i >> 3, cc = i & 7;
        uint4 v = *(const uint4*)(A + (size_t)r * 256 + k0 + cc * 8);
        *(uint4*)&As_[r * 64 + ((cc ^ (r & 7)) * 8)] = v;
      }
    }
#pragma unroll
    for (int l = 0; l < 8; ++l) {              // B: 2048 16B chunks
      int i = l * 256 + tid;
      int nn = i >> 3, cc = i & 7;
      uint4 v = *(const uint4*)(Wtq + (size_t)nn * 256 + k0 + cc * 8);
      *(uint4*)&Bs_[nn * 64 + ((cc ^ (nn & 7)) * 8)] = v;
    }
    __syncthreads();
#pragma unroll
    for (int kk = 0; kk < 2; ++kk) {
      const int offk = (((kk << 2) | ql) ^ l7) * 8;
      bf16x8 bfr[4];
#pragma unroll
      for (int ni = 0; ni < 4; ++ni)
        bfr[ni] = *(const bf16x8*)&Bs_[(w * 64 + ni * 16 + cl) * 64 + offk];
#pragma unroll
      for (int mi = 0; mi < 5; ++mi) {
        bf16x8 afr = *(const bf16x8*)&As_[(mi * 16 + cl) * 64 + offk];
#pragma unroll
        for (int ni = 0; ni < 4; ++ni)
          acc[mi][ni] = __builtin_amdgcn_mfma_f32_16x16x32_bf16(afr, bfr[ni], acc[mi][ni], 0, 0, 0);
      }
    }
  }
  __syncthreads();                             // staging reads done; reuse smem as qlds
#pragma unroll
  for (int mi = 0; mi < 5; ++mi)
#pragma unroll
    for (int ni = 0; ni < 4; ++ni)
#pragma unroll
      for (int rr = 0; rr < 4; ++rr)
        qlds[(mi * 64 + 16 * ql + 4 * rr + w) * 72 + ni * 16 + cl] = f2bf(acc[mi][ni][rr]);
  __syncthreads();

#pragma unroll
  for (int t = 0; t < 5; ++t) {
    f32x4 sacc[4];
#pragma unroll
    for (int si = 0; si < 4; ++si) {
      bf16x8 a0 = *(const bf16x8*)&qlds[(t * 64 + si * 16 + cl) * 72 + ql * 8];
      bf16x8 a1 = *(const bf16x8*)&qlds[(t * 64 + si * 16 + cl) * 72 + ql * 8 + 32];
      f32x4 z = (f32x4){0.f, 0.f, 0.f, 0.f};
      z = __builtin_amdgcn_mfma_f32_16x16x32_bf16(a0, kfr0, z, 0, 0, 0);
      z = __builtin_amdgcn_mfma_f32_16x16x32_bf16(a1, kfr1, z, 0, 0, 0);
      sacc[si] = z;
    }
    const float* pp = prior + t * 4096;
    float colsum = 0.f;
#pragma unroll
    for (int si = 0; si < 4; ++si) {
#pragma unroll
      for (int r = 0; r < 4; ++r) {
        int s = si * 16 + ql * 4 + r;
        float sg = 1.f / (1.f + __expf(-sacc[si][r] * 0.125f));
        colsum += sg * pp[s * 64 + c];
      }
    }
    colsum += __shfl_xor(colsum, 16);
    colsum += __shfl_xor(colsum, 32);
    if (ql == 0)
      ssum[(size_t)n * 320 + t * 64 + c] = colsum - bps[((size_t)nb * 5 + t) * 64 + c];
  }
}

// ---------------- fused v-GEMM + o-GEMM (fully LDS-staged) ------------------------
// One block = one (b,t) group: rows [g*64, g*64+64). 512 thr = 8 waves (2 rows x 4
// cols). Phase 1: V = xb @ Wv^T (staged As/Bs via gload16, source-XOR swizzle),
// scale by ssum, bf16 -> Vs [64][256] with chunk-XOR swizzle (ch ^= row&31).
// Phase 2: O = Vs @ Wo^T (Bs restaged over phase-1 Bs). Epilogue: ob + SE avg/max
// for this bt group (exactly one group per block). 1280 blocks = 2+/CU overlap.
__global__ __launch_bounds__(512, 2) void vo_gemm(const ushort_t* __restrict__ xb,
                                                  const ushort_t* __restrict__ Wtv,
                                                  const ushort_t* __restrict__ Wto,
                                                  const float* __restrict__ ssum,
                                                  ushort_t* __restrict__ ob,
                                                  float* __restrict__ ravg,
                                                  float* __restrict__ rmax) {
  __shared__ __align__(16) ushort_t As_[64 * 64];      // 8K
  __shared__ __align__(16) ushort_t Bs_[256 * 64];     // 32K
  __shared__ __align__(16) ushort_t Vs_[64 * 256];     // 32K
  __shared__ float redS[8], redM[8];
  const int tid = threadIdx.x;
  const int lane = tid & 63;
  const int w = tid >> 6, wr = w >> 2, wc = w & 3;
  const int g = blockIdx.x;                            // bt group, 1280 total
  const int row0 = g * 64;
  const int cl = lane & 15, ql = lane >> 4, l7 = lane & 7;

  f32x4 acc[2][4];
#pragma unroll
  for (int mi = 0; mi < 2; ++mi)
#pragma unroll
    for (int ni = 0; ni < 4; ++ni) acc[mi][ni] = (f32x4){0.f, 0.f, 0.f, 0.f};

  // ---- phase 1: V = xb @ Wv^T ----
  for (int t = 0; t < 4; ++t) {
    const int k0 = t * 64;
    if (t) __syncthreads();
    {                                          // A: 512 chunks, 1/thread
      int i = tid;
      int r = i >> 3, cpos = i & 7, csrc = cpos ^ (r & 7);
      gload16(xb + (size_t)(row0 + r) * 256 + k0 + csrc * 8, &As_[(w * 64) * 8]);
    }
#pragma unroll
    for (int l = 0; l < 4; ++l) {              // B: 2048 chunks
      int i = l * 512 + tid;
      int n = i >> 3, cpos = i & 7, csrc = cpos ^ (n & 7);
      gload16(Wtv + (size_t)n * 256 + k0 + csrc * 8, &Bs_[(l * 512 + w * 64) * 8]);
    }
    __syncthreads();
#pragma unroll
    for (int kk = 0; kk < 2; ++kk) {
      const int offk = (((kk << 2) | ql) ^ l7) * 8;
      bf16x8 bfr[4], afr[2];
#pragma unroll
      for (int ni = 0; ni < 4; ++ni)
        bfr[ni] = *(const bf16x8*)&Bs_[(wc * 64 + ni * 16 + cl) * 64 + offk];
#pragma unroll
      for (int mi = 0; mi < 2; ++mi)
        afr[mi] = *(const bf16x8*)&As_[(wr * 32 + mi * 16 + cl) * 64 + offk];
#pragma unroll
      for (int mi = 0; mi < 2; ++mi)
#pragma unroll
        for (int ni = 0; ni < 4; ++ni)
          acc[mi][ni] = __builtin_amdgcn_mfma_f32_16x16x32_bf16(afr[mi], bfr[ni], acc[mi][ni], 0, 0, 0);
    }
  }
  // scale + write Vs (chunk-XOR swizzled)
#pragma unroll
  for (int mi = 0; mi < 2; ++mi) {
    float sc[4];
#pragma unroll
    for (int r = 0; r < 4; ++r)
      sc[r] = ssum[(size_t)(row0 + wr * 32 + mi * 16 + ql * 4 + r) * 4 + wc];
#pragma unroll
    for (int ni = 0; ni < 4; ++ni) {
      int col = wc * 64 + ni * 16 + cl;
#pragma unroll
      for (int r = 0; r < 4; ++r) {
        int row = wr * 32 + mi * 16 + ql * 4 + r;
        int ch = (col >> 3) ^ (row & 31);
        Vs_[row * 256 + ch * 8 + (col & 7)] = f2bf(acc[mi][ni][r] * sc[r]);
      }
    }
  }
  __syncthreads();                             // Vs visible; phase-1 Bs reads done

  // ---- phase 2: O = Vs @ Wo^T ----
#pragma unroll
  for (int mi = 0; mi < 2; ++mi)
#pragma unroll
    for (int ni = 0; ni < 4; ++ni) acc[mi][ni] = (f32x4){0.f, 0.f, 0.f, 0.f};
  for (int t = 0; t < 4; ++t) {
    const int k0 = t * 64;
    if (t) __syncthreads();
#pragma unroll
    for (int l = 0; l < 4; ++l) {              // B: 2048 chunks (Wo)
      int i = l * 512 + tid;
      int n = i >> 3, cpos = i & 7, csrc = cpos ^ (n & 7);
      gload16(Wto + (size_t)n * 256 + k0 + csrc * 8, &Bs_[(l * 512 + w * 64) * 8]);
    }
    __syncthreads();
#pragma unroll
    for (int kk = 0; kk < 2; ++kk) {
      const int offk = (((kk << 2) | ql) ^ l7) * 8;
      const int ch = t * 8 + kk * 4 + ql;      // global k-chunk for Vs read
      bf16x8 bfr[4], afr[2];
#pragma unroll
      for (int ni = 0; ni < 4; ++ni)
        bfr[ni] = *(const bf16x8*)&Bs_[(wc * 64 + ni * 16 + cl) * 64 + offk];
#pragma unroll
      for (int mi = 0; mi < 2; ++mi) {
        int row = wr * 32 + mi * 16 + cl;
        afr[mi] = *(const bf16x8*)&Vs_[row * 256 + (ch ^ (row & 31)) * 8];
      }
#pragma unroll
      for (int mi = 0; mi < 2; ++mi)
#pragma unroll
        for (int ni = 0; ni < 4; ++ni)
          acc[mi][ni] = __builtin_amdgcn_mfma_f32_16x16x32_bf16(afr[mi], bfr[ni], acc[mi][ni], 0, 0, 0);
    }
  }
  // epilogue: write ob bf16 + SE avg/max over this block's bt group
  float lsum = 0.f, lmax = -3.4e38f;
#pragma unroll
  for (int mi = 0; mi < 2; ++mi)
#pragma unroll
    for (int ni = 0; ni < 4; ++ni) {
      int col = wc * 64 + ni * 16 + cl;
#pragma unroll
      for (int r = 0; r < 4; ++r) {
        int row = row0 + wr * 32 + mi * 16 + ql * 4 + r;
        float f = acc[mi][ni][r];
        ob[(size_t)row * 256 + col] = f2bf(f);
        lsum += f; lmax = fmaxf(lmax, f);
      }
    }
#pragma unroll
  for (int off = 32; off; off >>= 1) {
    lsum += __shfl_xor(lsum, off);
    lmax = fmaxf(lmax, __shfl_xor(lmax, off));
  }
  if (lane == 0) { redS[w] = lsum; redM[w] = lmax; }
  __syncthreads();
  if (tid == 0) {
    float s = 0.f, m = -3.4e38f;
#pragma unroll
    for (int i = 0; i < 8; ++i) { s += redS[i]; m = fmaxf(m, redM[i]); }
    ravg[g] = s * (1.f / 16384.f);
    rmax[g] = m;
  }
}

// ---------------- final: out = bf16(o)*se[b,t] + bf16(x), se computed inline ------
__global__ __launch_bounds__(256) void final_kernel(
    const ushort_t* __restrict__ xb, const ushort_t* __restrict__ ob,
    const float* __restrict__ ravg, const float* __restrict__ rmax,
    const float* __restrict__ fc1w, const float* __restrict__ fc1b,
    const float* __restrict__ fc2w, const float* __restrict__ fc2b,
    const float* __restrict__ bili, float* __restrict__ out) {
  __shared__ float sse;
  int i = blockIdx.x * 256 + threadIdx.x;      // float4 id, 5242880
  size_t j = (size_t)i * 4;
  int bt = (int)(j >> 14);
  uint2 uo = *(const uint2*)(ob + j);          // issue loads before serial SE
  uint2 ux = *(const uint2*)(xb + j);
  if (threadIdx.x == 0) {
    int b = bt / 5, t = bt % 5;
    float avg[5], mx[5];
    for (int tt = 0; tt < 5; ++tt) { avg[tt] = ravg[b * 5 + tt]; mx[tt] = rmax[b * 5 + tt]; }
    float w = bili[0];
    float s12[2];
    for (int p = 0; p < 2; ++p) {
      const float* in = p == 0 ? avg : mx;
      float a = fc2b[t];
      for (int jj = 0; jj < 25; ++jj) {
        float hh = fc1b[jj];
        for (int tt = 0; tt < 5; ++tt) hh += in[tt] * fc1w[tt * 25 + jj];
        a += fmaxf(hh, 0.f) * fc2w[jj * 5 + t];
      }
      s12[p] = 1.f / (1.f + __expf(-a));
    }
    sse = (1.f - w) * s12[0] + w * s12[1];
  }
  __syncthreads();
  float s = sse;
  float4 r = {bflo(uo.x) * s + bflo(ux.x), bfhi(uo.x) * s + bfhi(ux.x),
              bflo(uo.y) * s + bflo(ux.y), bfhi(uo.y) * s + bfhi(ux.y)};
  *(float4*)(out + j) = r;
}

extern "C" void kernel_launch(void* const* d_in, const int* in_sizes, int n_in,
                              void* d_out, int out_size, void* d_ws, size_t ws_size,
                              hipStream_t stream) {
  const float* x     = (const float*)d_in[0];
  const float* bias  = (const float*)d_in[1];
  const float* Wq    = (const float*)d_in[2];
  const float* Wv    = (const float*)d_in[3];
  const float* Wo    = (const float*)d_in[4];
  const float* u_t   = (const float*)d_in[5];
  const float* dis   = (const float*)d_in[6];
  const float* sigma = (const float*)d_in[7];
  const float* fc1w  = (const float*)d_in[8];
  const float* fc1b  = (const float*)d_in[9];
  const float* fc2w  = (const float*)d_in[10];
  const float* fc2b  = (const float*)d_in[11];
  const float* bili  = (const float*)d_in[12];
  float* out = (float*)d_out;

  // workspace layout (bytes), ~94.5 MB. qvb holds o only (v never touches HBM).
  char* wsb = (char*)d_ws;
  ushort_t* xbuf = (ushort_t*)wsb;             wsb += 41943040;  // bf16(x), alive to end
  ushort_t* qvb  = (ushort_t*)wsb;             wsb += 41943040;  // o bf16
  ushort_t* kb   = (ushort_t*)wsb;             wsb += 8388608;   // k bf16 [B,S,F]
  ushort_t* Wt   = (ushort_t*)wsb;             wsb += 393216;    // 3 x W^T bf16
  float*    ssum = (float*)wsb;                wsb += 1310720;
  float*    prior= (float*)wsb;                wsb += 81920;
  float*    bps  = (float*)wsb;                wsb += 327680;
  float*    ravg = (float*)wsb;                wsb += 5120;
  float*    rmax = (float*)wsb;                wsb += 5120;

  // 1) fused prep: Wt | prior | bps | (k, xb)
  prep_kernel<<<4176, 256, 0, stream>>>(x, u_t, Wq, Wv, Wo, dis, sigma, bias,
                                        Wt, prior, bps, kb, xbuf);
  // 2) fused q-GEMM + score (q never touches HBM)
  qscore<<<1024, 256, 0, stream>>>(xbuf, Wt, kb, prior, bps, ssum);
  // 3) fused v-GEMM + o-GEMM (v never touches HBM), SE avg/max in epilogue
  vo_gemm<<<1280, 512, 0, stream>>>(xbuf, Wt + 65536, Wt + 131072, ssum,
                                    qvb, ravg, rmax);
  // 4) final with inline SE MLP
  final_kernel<<<20480, 256, 0, stream>>>(xbuf, qvb, ravg, rmax,
                                          fc1w, fc1b, fc2w, fc2b, bili, out);
}

// Round 23
// 144.555 us; speedup vs baseline: 1.1812x; 1.0010x over previous
//
#include <hip/hip_runtime.h>

// B=256, T=5, S=64, F=256, H=4, Fh=64, N=H*B=1024, M=81920 rows of [.,256]

typedef unsigned short ushort_t;
typedef __attribute__((ext_vector_type(8))) short bf16x8;
typedef __attribute__((ext_vector_type(4))) float f32x4;

__device__ inline ushort_t f2bf(float f) {            // RNE f32 -> bf16
  unsigned u = __float_as_uint(f);
  return (ushort_t)((u + 0x7FFFu + ((u >> 16) & 1u)) >> 16);
}
__device__ inline float bflo(unsigned u) { return __uint_as_float(u << 16); }
__device__ inline float bfhi(unsigned u) { return __uint_as_float(u & 0xFFFF0000u); }
__device__ inline uint4 pack8(float4 a, float4 b) {   // 8 f32 -> 8 bf16 in uint4
  uint4 r;
  r.x = (unsigned)f2bf(a.x) | ((unsigned)f2bf(a.y) << 16);
  r.y = (unsigned)f2bf(a.z) | ((unsigned)f2bf(a.w) << 16);
  r.z = (unsigned)f2bf(b.x) | ((unsigned)f2bf(b.y) << 16);
  r.w = (unsigned)f2bf(b.z) | ((unsigned)f2bf(b.w) << 16);
  return r;
}
// async global->LDS, 16B per lane; LDS dest = wave-uniform base + lane*16
__device__ inline void gload16(const ushort_t* g, ushort_t* l) {
  __builtin_amdgcn_global_load_lds((const __attribute__((address_space(1))) void*)g,
                                   (__attribute__((address_space(3))) void*)l, 16, 0, 0);
}

// ---------------- fused prep: convert_w | prior | bias_prior_sum | k/xb -----------
// x-pass: the empty input-only asm pins all 10 float4 loads live BEFORE any
// store/FMA, forcing back-to-back issue (r12 PMC: VGPR=28 proved the scheduler
// serialized into load->store per t, ~2 loads in flight -> 2 TB/s).
__global__ __launch_bounds__(256, 4) void prep_kernel(
    const float* __restrict__ x, const float* __restrict__ u,
    const float* __restrict__ Wq, const float* __restrict__ Wv,
    const float* __restrict__ Wo, const float* __restrict__ dis,
    const float* __restrict__ sigma, const float* __restrict__ bias,
    ushort_t* __restrict__ Wt, float* __restrict__ prior,
    float* __restrict__ bps, ushort_t* __restrict__ kout,
    ushort_t* __restrict__ xb) {
  __shared__ float red[4][64];
  const int blk = blockIdx.x, tid = threadIdx.x;
  if (blk < 768) {
    int id = blk * 256 + tid;                  // 196608
    int mat = id >> 16, rem = id & 65535;
    int n = rem >> 8, k = rem & 255;
    const float* W = mat == 0 ? Wq : (mat == 1 ? Wv : Wo);
    Wt[id] = f2bf(W[k * 256 + n]);
  } else if (blk < 848) {
    int i = (blk - 768) * 256 + tid;           // 20480
    int ts = i >> 6;
    float sg = sigma[ts];
    float d = dis[i];
    prior[i] = 0.3989422804014327f / sg * __expf(-d * d / (2.f * sg * sg));
  } else if (blk < 2128) {
    int b2 = blk - 848;                        // nb*5 + t, 1280 blocks
    int t = b2 % 5;
    const float* bp = bias + (size_t)b2 * 4096;
    int c = tid & 63, sg_ = tid >> 6;
    float sum = 0.f;
    for (int s = sg_ * 16; s < sg_ * 16 + 16; ++s) {
      float sgm = sigma[t * 64 + s];
      float d = dis[t * 4096 + s * 64 + c];
      float pr = 0.3989422804014327f / sgm * __expf(-d * d / (2.f * sgm * sgm));
      sum += bp[s * 64 + c] * pr;
    }
    red[sg_][c] = sum;
    __syncthreads();
    if (tid < 64)
      bps[(size_t)b2 * 64 + tid] = red[0][tid] + red[1][tid] + red[2][tid] + red[3][tid];
  } else {
    int i = (blk - 2128) * 256 + tid;          // 8-float id, 524288 total
    size_t j = (size_t)i * 8;
    int b = (int)(j >> 14);
    int off = (int)(j & 16383);
    const float* xp = x + (size_t)b * 81920 + off;
    ushort_t* xq = xb + (size_t)b * 81920 + off;
    float u0 = u[0], u1 = u[1], u2 = u[2], u3 = u[3], u4 = u[4];
    float4 lo[5], hi[5];
#pragma unroll
    for (int t = 0; t < 5; ++t) {
      lo[t] = *(const float4*)(xp + t * 16384);
      hi[t] = *(const float4*)(xp + t * 16384 + 4);
    }
    // scheduling fence: all 10 loads must be complete (values live) here
#pragma unroll
    for (int t = 0; t < 5; ++t)
      asm volatile("" :: "v"(lo[t].x), "v"(lo[t].y), "v"(lo[t].z), "v"(lo[t].w),
                         "v"(hi[t].x), "v"(hi[t].y), "v"(hi[t].z), "v"(hi[t].w));
#pragma unroll
    for (int t = 0; t < 5; ++t)
      *(uint4*)(xq + t * 16384) = pack8(lo[t], hi[t]);
    float4 rl, rh;
    rl.x = u0*lo[0].x + u1*lo[1].x + u2*lo[2].x + u3*lo[3].x + u4*lo[4].x;
    rl.y = u0*lo[0].y + u1*lo[1].y + u2*lo[2].y + u3*lo[3].y + u4*lo[4].y;
    rl.z = u0*lo[0].z + u1*lo[1].z + u2*lo[2].z + u3*lo[3].z + u4*lo[4].z;
    rl.w = u0*lo[0].w + u1*lo[1].w + u2*lo[2].w + u3*lo[3].w + u4*lo[4].w;
    rh.x = u0*hi[0].x + u1*hi[1].x + u2*hi[2].x + u3*hi[3].x + u4*hi[4].x;
    rh.y = u0*hi[0].y + u1*hi[1].y + u2*hi[2].y + u3*hi[3].y + u4*hi[4].y;
    rh.z = u0*hi[0].z + u1*hi[1].z + u2*hi[2].z + u3*hi[3].z + u4*hi[4].z;
    rh.w = u0*hi[0].w + u1*hi[1].w + u2*hi[2].w + u3*hi[3].w + u4*hi[4].w;
    *(uint4*)(kout + j) = pack8(rl, rh);
  }
}

// ---------------- fused q-GEMM + score (LDS-staged) -------------------------------
__global__ __launch_bounds__(256) void qscore(const ushort_t* __restrict__ xb,
                                              const ushort_t* __restrict__ Wtq,
                                              const ushort_t* __restrict__ kbuf,
                                              const float* __restrict__ prior,
                                              const float* __restrict__ bps,
                                              float* __restrict__ ssum) {
  __shared__ __align__(16) char smem[46080];           // union: As+Bs (43K) | qlds (45K)
  ushort_t* As_ = (ushort_t*)smem;                     // [80*64]
  ushort_t* Bs_ = (ushort_t*)(smem + 10240);           // [256*64]
  ushort_t* qlds = (ushort_t*)smem;                    // [5*64*72]
  const int n = blockIdx.x;
  const int tid = threadIdx.x;
  const int lane = tid & 63, w = tid >> 6;
  const int cl = lane & 15, ql = lane >> 4, l7 = lane & 7;
  const ushort_t* A = xb + (size_t)n * 20480;          // 80 rows x 256

  const int c = w * 16 + cl;
  const int nb = n & 255;
  const ushort_t* kbp = kbuf + (size_t)(n >> 2) * 16384 + (n & 3) * 64;
  bf16x8 kfr0 = *(const bf16x8*)(kbp + c * 256 + ql * 8);
  bf16x8 kfr1 = *(const bf16x8*)(kbp + c * 256 + ql * 8 + 32);

  f32x4 acc[5][4];
#pragma unroll
  for (int mi = 0; mi < 5; ++mi)
#pragma unroll
    for (int ni = 0; ni < 4; ++ni) acc[mi][ni] = (f32x4){0.f, 0.f, 0.f, 0.f};

  for (int t4 = 0; t4 < 4; ++t4) {
    const int k0 = t4 * 64;
    if (t4) __syncthreads();
#pragma unroll
    for (int l = 0; l < 3; ++l) {              // A: 640 16B chunks
      int i = l * 256 + tid;
      if (i < 640) {
        int r = i >> 3, cc = i & 7;
        uint4 v = *(const uint4*)(A + (size_t)r * 256 + k0 + cc * 8);
        *(uint4*)&As_[r * 64 + ((cc ^ (r & 7)) * 8)] = v;
      }
    }
#pragma unroll
    for (int l = 0; l < 8; ++l) {              // B: 2048 16B chunks
      int i = l * 256 + tid;
      int nn = i >> 3, cc = i & 7;
      uint4 v = *(const uint4*)(Wtq + (size_t)nn * 256 + k0 + cc * 8);
      *(uint4*)&Bs_[nn * 64 + ((cc ^ (nn & 7)) * 8)] = v;
    }
    __syncthreads();
#pragma unroll
    for (int kk = 0; kk < 2; ++kk) {
      const int offk = (((kk << 2) | ql) ^ l7) * 8;
      bf16x8 bfr[4];
#pragma unroll
      for (int ni = 0; ni < 4; ++ni)
        bfr[ni] = *(const bf16x8*)&Bs_[(w * 64 + ni * 16 + cl) * 64 + offk];
#pragma unroll
      for (int mi = 0; mi < 5; ++mi) {
        bf16x8 afr = *(const bf16x8*)&As_[(mi * 16 + cl) * 64 + offk];
#pragma unroll
        for (int ni = 0; ni < 4; ++ni)
          acc[mi][ni] = __builtin_amdgcn_mfma_f32_16x16x32_bf16(afr, bfr[ni], acc[mi][ni], 0, 0, 0);
      }
    }
  }
  __syncthreads();                             // staging reads done; reuse smem as qlds
#pragma unroll
  for (int mi = 0; mi < 5; ++mi)
#pragma unroll
    for (int ni = 0; ni < 4; ++ni)
#pragma unroll
      for (int rr = 0; rr < 4; ++rr)
        qlds[(mi * 64 + 16 * ql + 4 * rr + w) * 72 + ni * 16 + cl] = f2bf(acc[mi][ni][rr]);
  __syncthreads();

#pragma unroll
  for (int t = 0; t < 5; ++t) {
    f32x4 sacc[4];
#pragma unroll
    for (int si = 0; si < 4; ++si) {
      bf16x8 a0 = *(const bf16x8*)&qlds[(t * 64 + si * 16 + cl) * 72 + ql * 8];
      bf16x8 a1 = *(const bf16x8*)&qlds[(t * 64 + si * 16 + cl) * 72 + ql * 8 + 32];
      f32x4 z = (f32x4){0.f, 0.f, 0.f, 0.f};
      z = __builtin_amdgcn_mfma_f32_16x16x32_bf16(a0, kfr0, z, 0, 0, 0);
      z = __builtin_amdgcn_mfma_f32_16x16x32_bf16(a1, kfr1, z, 0, 0, 0);
      sacc[si] = z;
    }
    const float* pp = prior + t * 4096;
    float colsum = 0.f;
#pragma unroll
    for (int si = 0; si < 4; ++si) {
#pragma unroll
      for (int r = 0; r < 4; ++r) {
        int s = si * 16 + ql * 4 + r;
        float sg = 1.f / (1.f + __expf(-sacc[si][r] * 0.125f));
        colsum += sg * pp[s * 64 + c];
      }
    }
    colsum += __shfl_xor(colsum, 16);
    colsum += __shfl_xor(colsum, 32);
    if (ql == 0)
      ssum[(size_t)n * 320 + t * 64 + c] = colsum - bps[((size_t)nb * 5 + t) * 64 + c];
  }
}

// ---------------- fused v-GEMM + o-GEMM (fully LDS-staged) ------------------------
__global__ __launch_bounds__(512, 2) void vo_gemm(const ushort_t* __restrict__ xb,
                                                  const ushort_t* __restrict__ Wtv,
                                                  const ushort_t* __restrict__ Wto,
                                                  const float* __restrict__ ssum,
                                                  ushort_t* __restrict__ ob,
                                                  float* __restrict__ ravg,
                                                  float* __restrict__ rmax) {
  __shared__ __align__(16) ushort_t As_[64 * 64];      // 8K
  __shared__ __align__(16) ushort_t Bs_[256 * 64];     // 32K
  __shared__ __align__(16) ushort_t Vs_[64 * 256];     // 32K
  __shared__ float redS[8], redM[8];
  const int tid = threadIdx.x;
  const int lane = tid & 63;
  const int w = tid >> 6, wr = w >> 2, wc = w & 3;
  const int g = blockIdx.x;                            // bt group, 1280 total
  const int row0 = g * 64;
  const int cl = lane & 15, ql = lane >> 4, l7 = lane & 7;

  f32x4 acc[2][4];
#pragma unroll
  for (int mi = 0; mi < 2; ++mi)
#pragma unroll
    for (int ni = 0; ni < 4; ++ni) acc[mi][ni] = (f32x4){0.f, 0.f, 0.f, 0.f};

  // ---- phase 1: V = xb @ Wv^T ----
  for (int t = 0; t < 4; ++t) {
    const int k0 = t * 64;
    if (t) __syncthreads();
    {                                          // A: 512 chunks, 1/thread
      int i = tid;
      int r = i >> 3, cpos = i & 7, csrc = cpos ^ (r & 7);
      gload16(xb + (size_t)(row0 + r) * 256 + k0 + csrc * 8, &As_[(w * 64) * 8]);
    }
#pragma unroll
    for (int l = 0; l < 4; ++l) {              // B: 2048 chunks
      int i = l * 512 + tid;
      int n = i >> 3, cpos = i & 7, csrc = cpos ^ (n & 7);
      gload16(Wtv + (size_t)n * 256 + k0 + csrc * 8, &Bs_[(l * 512 + w * 64) * 8]);
    }
    __syncthreads();
#pragma unroll
    for (int kk = 0; kk < 2; ++kk) {
      const int offk = (((kk << 2) | ql) ^ l7) * 8;
      bf16x8 bfr[4], afr[2];
#pragma unroll
      for (int ni = 0; ni < 4; ++ni)
        bfr[ni] = *(const bf16x8*)&Bs_[(wc * 64 + ni * 16 + cl) * 64 + offk];
#pragma unroll
      for (int mi = 0; mi < 2; ++mi)
        afr[mi] = *(const bf16x8*)&As_[(wr * 32 + mi * 16 + cl) * 64 + offk];
#pragma unroll
      for (int mi = 0; mi < 2; ++mi)
#pragma unroll
        for (int ni = 0; ni < 4; ++ni)
          acc[mi][ni] = __builtin_amdgcn_mfma_f32_16x16x32_bf16(afr[mi], bfr[ni], acc[mi][ni], 0, 0, 0);
    }
  }
  // scale + write Vs (chunk-XOR swizzled)
#pragma unroll
  for (int mi = 0; mi < 2; ++mi) {
    float sc[4];
#pragma unroll
    for (int r = 0; r < 4; ++r)
      sc[r] = ssum[(size_t)(row0 + wr * 32 + mi * 16 + ql * 4 + r) * 4 + wc];
#pragma unroll
    for (int ni = 0; ni < 4; ++ni) {
      int col = wc * 64 + ni * 16 + cl;
#pragma unroll
      for (int r = 0; r < 4; ++r) {
        int row = wr * 32 + mi * 16 + ql * 4 + r;
        int ch = (col >> 3) ^ (row & 31);
        Vs_[row * 256 + ch * 8 + (col & 7)] = f2bf(acc[mi][ni][r] * sc[r]);
      }
    }
  }
  __syncthreads();                             // Vs visible; phase-1 Bs reads done

  // ---- phase 2: O = Vs @ Wo^T ----
#pragma unroll
  for (int mi = 0; mi < 2; ++mi)
#pragma unroll
    for (int ni = 0; ni < 4; ++ni) acc[mi][ni] = (f32x4){0.f, 0.f, 0.f, 0.f};
  for (int t = 0; t < 4; ++t) {
    const int k0 = t * 64;
    if (t) __syncthreads();
#pragma unroll
    for (int l = 0; l < 4; ++l) {              // B: 2048 chunks (Wo)
      int i = l * 512 + tid;
      int n = i >> 3, cpos = i & 7, csrc = cpos ^ (n & 7);
      gload16(Wto + (size_t)n * 256 + k0 + csrc * 8, &Bs_[(l * 512 + w * 64) * 8]);
    }
    __syncthreads();
#pragma unroll
    for (int kk = 0; kk < 2; ++kk) {
      const int offk = (((kk << 2) | ql) ^ l7) * 8;
      const int ch = t * 8 + kk * 4 + ql;      // global k-chunk for Vs read
      bf16x8 bfr[4], afr[2];
#pragma unroll
      for (int ni = 0; ni < 4; ++ni)
        bfr[ni] = *(const bf16x8*)&Bs_[(wc * 64 + ni * 16 + cl) * 64 + offk];
#pragma unroll
      for (int mi = 0; mi < 2; ++mi) {
        int row = wr * 32 + mi * 16 + cl;
        afr[mi] = *(const bf16x8*)&Vs_[row * 256 + (ch ^ (row & 31)) * 8];
      }
#pragma unroll
      for (int mi = 0; mi < 2; ++mi)
#pragma unroll
        for (int ni = 0; ni < 4; ++ni)
          acc[mi][ni] = __builtin_amdgcn_mfma_f32_16x16x32_bf16(afr[mi], bfr[ni], acc[mi][ni], 0, 0, 0);
    }
  }
  // epilogue: write ob bf16 + SE avg/max over this block's bt group
  float lsum = 0.f, lmax = -3.4e38f;
#pragma unroll
  for (int mi = 0; mi < 2; ++mi)
#pragma unroll
    for (int ni = 0; ni < 4; ++ni) {
      int col = wc * 64 + ni * 16 + cl;
#pragma unroll
      for (int r = 0; r < 4; ++r) {
        int row = row0 + wr * 32 + mi * 16 + ql * 4 + r;
        float f = acc[mi][ni][r];
        ob[(size_t)row * 256 + col] = f2bf(f);
        lsum += f; lmax = fmaxf(lmax, f);
      }
    }
#pragma unroll
  for (int off = 32; off; off >>= 1) {
    lsum += __shfl_xor(lsum, off);
    lmax = fmaxf(lmax, __shfl_xor(lmax, off));
  }
  if (lane == 0) { redS[w] = lsum; redM[w] = lmax; }
  __syncthreads();
  if (tid == 0) {
    float s = 0.f, m = -3.4e38f;
#pragma unroll
    for (int i = 0; i < 8; ++i) { s += redS[i]; m = fmaxf(m, redM[i]); }
    ravg[g] = s * (1.f / 16384.f);
    rmax[g] = m;
  }
}

// ---------------- final: out = bf16(o)*se[b,t] + bf16(x), se computed inline ------
__global__ __launch_bounds__(256) void final_kernel(
    const ushort_t* __restrict__ xb, const ushort_t* __restrict__ ob,
    const float* __restrict__ ravg, const float* __restrict__ rmax,
    const float* __restrict__ fc1w, const float* __restrict__ fc1b,
    const float* __restrict__ fc2w, const float* __restrict__ fc2b,
    const float* __restrict__ bili, float* __restrict__ out) {
  __shared__ float sse;
  int i = blockIdx.x * 256 + threadIdx.x;      // float4 id, 5242880
  size_t j = (size_t)i * 4;
  int bt = (int)(j >> 14);
  uint2 uo = *(const uint2*)(ob + j);          // issue loads before serial SE
  uint2 ux = *(const uint2*)(xb + j);
  if (threadIdx.x == 0) {
    int b = bt / 5, t = bt % 5;
    float avg[5], mx[5];
    for (int tt = 0; tt < 5; ++tt) { avg[tt] = ravg[b * 5 + tt]; mx[tt] = rmax[b * 5 + tt]; }
    float w = bili[0];
    float s12[2];
    for (int p = 0; p < 2; ++p) {
      const float* in = p == 0 ? avg : mx;
      float a = fc2b[t];
      for (int jj = 0; jj < 25; ++jj) {
        float hh = fc1b[jj];
        for (int tt = 0; tt < 5; ++tt) hh += in[tt] * fc1w[tt * 25 + jj];
        a += fmaxf(hh, 0.f) * fc2w[jj * 5 + t];
      }
      s12[p] = 1.f / (1.f + __expf(-a));
    }
    sse = (1.f - w) * s12[0] + w * s12[1];
  }
  __syncthreads();
  float s = sse;
  float4 r = {bflo(uo.x) * s + bflo(ux.x), bfhi(uo.x) * s + bfhi(ux.x),
              bflo(uo.y) * s + bflo(ux.y), bfhi(uo.y) * s + bfhi(ux.y)};
  *(float4*)(out + j) = r;
}

extern "C" void kernel_launch(void* const* d_in, const int* in_sizes, int n_in,
                              void* d_out, int out_size, void* d_ws, size_t ws_size,
                              hipStream_t stream) {
  const float* x     = (const float*)d_in[0];
  const float* bias  = (const float*)d_in[1];
  const float* Wq    = (const float*)d_in[2];
  const float* Wv    = (const float*)d_in[3];
  const float* Wo    = (const float*)d_in[4];
  const float* u_t   = (const float*)d_in[5];
  const float* dis   = (const float*)d_in[6];
  const float* sigma = (const float*)d_in[7];
  const float* fc1w  = (const float*)d_in[8];
  const float* fc1b  = (const float*)d_in[9];
  const float* fc2w  = (const float*)d_in[10];
  const float* fc2b  = (const float*)d_in[11];
  const float* bili  = (const float*)d_in[12];
  float* out = (float*)d_out;

  // workspace layout (bytes), ~94.5 MB. qvb holds o only (v never touches HBM).
  char* wsb = (char*)d_ws;
  ushort_t* xbuf = (ushort_t*)wsb;             wsb += 41943040;  // bf16(x), alive to end
  ushort_t* qvb  = (ushort_t*)wsb;             wsb += 41943040;  // o bf16
  ushort_t* kb   = (ushort_t*)wsb;             wsb += 8388608;   // k bf16 [B,S,F]
  ushort_t* Wt   = (ushort_t*)wsb;             wsb += 393216;    // 3 x W^T bf16
  float*    ssum = (float*)wsb;                wsb += 1310720;
  float*    prior= (float*)wsb;                wsb += 81920;
  float*    bps  = (float*)wsb;                wsb += 327680;
  float*    ravg = (float*)wsb;                wsb += 5120;
  float*    rmax = (float*)wsb;                wsb += 5120;

  // 1) fused prep: Wt | prior | bps | (k, xb)
  prep_kernel<<<4176, 256, 0, stream>>>(x, u_t, Wq, Wv, Wo, dis, sigma, bias,
                                        Wt, prior, bps, kb, xbuf);
  // 2) fused q-GEMM + score (q never touches HBM)
  qscore<<<1024, 256, 0, stream>>>(xbuf, Wt, kb, prior, bps, ssum);
  // 3) fused v-GEMM + o-GEMM (v never touches HBM), SE avg/max in epilogue
  vo_gemm<<<1280, 512, 0, stream>>>(xbuf, Wt + 65536, Wt + 131072, ssum,
                                    qvb, ravg, rmax);
  // 4) final with inline SE MLP
  final_kernel<<<20480, 256, 0, stream>>>(xbuf, qvb, ravg, rmax,
                                          fc1w, fc1b, fc2w, fc2b, bili, out);
}

// Round 25
// 142.057 us; speedup vs baseline: 1.2019x; 1.0176x over previous
//
#include <hip/hip_runtime.h>

// B=256, T=5, S=64, F=256, H=4, Fh=64, N=H*B=1024, M=81920 rows of [.,256]

typedef unsigned short ushort_t;
typedef __attribute__((ext_vector_type(8))) short bf16x8;
typedef __attribute__((ext_vector_type(4))) float f32x4;
typedef __attribute__((ext_vector_type(4))) unsigned int u32x4;

__device__ inline ushort_t f2bf(float f) {            // RNE f32 -> bf16
  unsigned u = __float_as_uint(f);
  return (ushort_t)((u + 0x7FFFu + ((u >> 16) & 1u)) >> 16);
}
__device__ inline float bflo(unsigned u) { return __uint_as_float(u << 16); }
__device__ inline float bfhi(unsigned u) { return __uint_as_float(u & 0xFFFF0000u); }
__device__ inline uint4 pack8(float4 a, float4 b) {   // 8 f32 -> 8 bf16 in uint4
  uint4 r;
  r.x = (unsigned)f2bf(a.x) | ((unsigned)f2bf(a.y) << 16);
  r.y = (unsigned)f2bf(a.z) | ((unsigned)f2bf(a.w) << 16);
  r.z = (unsigned)f2bf(b.x) | ((unsigned)f2bf(b.y) << 16);
  r.w = (unsigned)f2bf(b.z) | ((unsigned)f2bf(b.w) << 16);
  return r;
}
// async global->LDS, 16B per lane; LDS dest = wave-uniform base + lane*16
__device__ inline void gload16(const ushort_t* g, ushort_t* l) {
  __builtin_amdgcn_global_load_lds((const __attribute__((address_space(1))) void*)g,
                                   (__attribute__((address_space(3))) void*)l, 16, 0, 0);
}
__device__ inline void ntstore16(void* p, uint4 v) {  // no-allocate streaming store
  u32x4 w = {v.x, v.y, v.z, v.w};
  __builtin_nontemporal_store(w, (u32x4*)p);
}

// ---------------- fused prep: convert_w | prior | bias_prior_sum | k/xb -----------
// xb/k stores are non-temporal: not re-read within prep; keeps L2 free for the
// concurrent 84 MB x read stream.
__global__ __launch_bounds__(256, 4) void prep_kernel(
    const float* __restrict__ x, const float* __restrict__ u,
    const float* __restrict__ Wq, const float* __restrict__ Wv,
    const float* __restrict__ Wo, const float* __restrict__ dis,
    const float* __restrict__ sigma, const float* __restrict__ bias,
    ushort_t* __restrict__ Wt, float* __restrict__ prior,
    float* __restrict__ bps, ushort_t* __restrict__ kout,
    ushort_t* __restrict__ xb) {
  __shared__ float red[4][64];
  const int blk = blockIdx.x, tid = threadIdx.x;
  if (blk < 768) {
    int id = blk * 256 + tid;                  // 196608
    int mat = id >> 16, rem = id & 65535;
    int n = rem >> 8, k = rem & 255;
    const float* W = mat == 0 ? Wq : (mat == 1 ? Wv : Wo);
    Wt[id] = f2bf(W[k * 256 + n]);
  } else if (blk < 848) {
    int i = (blk - 768) * 256 + tid;           // 20480
    int ts = i >> 6;
    float sg = sigma[ts];
    float d = dis[i];
    prior[i] = 0.3989422804014327f / sg * __expf(-d * d / (2.f * sg * sg));
  } else if (blk < 2128) {
    int b2 = blk - 848;                        // nb*5 + t, 1280 blocks
    int t = b2 % 5;
    const float* bp = bias + (size_t)b2 * 4096;
    int c = tid & 63, sg_ = tid >> 6;
    float sum = 0.f;
    for (int s = sg_ * 16; s < sg_ * 16 + 16; ++s) {
      float sgm = sigma[t * 64 + s];
      float d = dis[t * 4096 + s * 64 + c];
      float pr = 0.3989422804014327f / sgm * __expf(-d * d / (2.f * sgm * sgm));
      sum += bp[s * 64 + c] * pr;
    }
    red[sg_][c] = sum;
    __syncthreads();
    if (tid < 64)
      bps[(size_t)b2 * 64 + tid] = red[0][tid] + red[1][tid] + red[2][tid] + red[3][tid];
  } else {
    int i = (blk - 2128) * 256 + tid;          // 8-float id, 524288 total
    size_t j = (size_t)i * 8;
    int b = (int)(j >> 14);
    int off = (int)(j & 16383);
    const float* xp = x + (size_t)b * 81920 + off;
    ushort_t* xq = xb + (size_t)b * 81920 + off;
    float u0 = u[0], u1 = u[1], u2 = u[2], u3 = u[3], u4 = u[4];
    float4 lo[5], hi[5];
#pragma unroll
    for (int t = 0; t < 5; ++t) {
      lo[t] = *(const float4*)(xp + t * 16384);
      hi[t] = *(const float4*)(xp + t * 16384 + 4);
    }
#pragma unroll
    for (int t = 0; t < 5; ++t)
      ntstore16(xq + t * 16384, pack8(lo[t], hi[t]));
    float4 rl, rh;
    rl.x = u0*lo[0].x + u1*lo[1].x + u2*lo[2].x + u3*lo[3].x + u4*lo[4].x;
    rl.y = u0*lo[0].y + u1*lo[1].y + u2*lo[2].y + u3*lo[3].y + u4*lo[4].y;
    rl.z = u0*lo[0].z + u1*lo[1].z + u2*lo[2].z + u3*lo[3].z + u4*lo[4].z;
    rl.w = u0*lo[0].w + u1*lo[1].w + u2*lo[2].w + u3*lo[3].w + u4*lo[4].w;
    rh.x = u0*hi[0].x + u1*hi[1].x + u2*hi[2].x + u3*hi[3].x + u4*hi[4].x;
    rh.y = u0*hi[0].y + u1*hi[1].y + u2*hi[2].y + u3*hi[3].y + u4*hi[4].y;
    rh.z = u0*hi[0].z + u1*hi[1].z + u2*hi[2].z + u3*hi[3].z + u4*hi[4].z;
    rh.w = u0*hi[0].w + u1*hi[1].w + u2*hi[2].w + u3*hi[3].w + u4*hi[4].w;
    ntstore16(kout + j, pack8(rl, rh));
  }
}

// ---------------- fused q-GEMM + score (LDS-staged) -------------------------------
__global__ __launch_bounds__(256) void qscore(const ushort_t* __restrict__ xb,
                                              const ushort_t* __restrict__ Wtq,
                                              const ushort_t* __restrict__ kbuf,
                                              const float* __restrict__ prior,
                                              const float* __restrict__ bps,
                                              float* __restrict__ ssum) {
  __shared__ __align__(16) char smem[46080];           // union: As+Bs (43K) | qlds (45K)
  ushort_t* As_ = (ushort_t*)smem;                     // [80*64]
  ushort_t* Bs_ = (ushort_t*)(smem + 10240);           // [256*64]
  ushort_t* qlds = (ushort_t*)smem;                    // [5*64*72]
  const int n = blockIdx.x;
  const int tid = threadIdx.x;
  const int lane = tid & 63, w = tid >> 6;
  const int cl = lane & 15, ql = lane >> 4, l7 = lane & 7;
  const ushort_t* A = xb + (size_t)n * 20480;          // 80 rows x 256

  const int c = w * 16 + cl;
  const int nb = n & 255;
  const ushort_t* kbp = kbuf + (size_t)(n >> 2) * 16384 + (n & 3) * 64;
  bf16x8 kfr0 = *(const bf16x8*)(kbp + c * 256 + ql * 8);
  bf16x8 kfr1 = *(const bf16x8*)(kbp + c * 256 + ql * 8 + 32);

  f32x4 acc[5][4];
#pragma unroll
  for (int mi = 0; mi < 5; ++mi)
#pragma unroll
    for (int ni = 0; ni < 4; ++ni) acc[mi][ni] = (f32x4){0.f, 0.f, 0.f, 0.f};

  for (int t4 = 0; t4 < 4; ++t4) {
    const int k0 = t4 * 64;
    if (t4) __syncthreads();
#pragma unroll
    for (int l = 0; l < 3; ++l) {              // A: 640 16B chunks
      int i = l * 256 + tid;
      if (i < 640) {
        int r = i >> 3, cc = i & 7;
        uint4 v = *(const uint4*)(A + (size_t)r * 256 + k0 + cc * 8);
        *(uint4*)&As_[r * 64 + ((cc ^ (r & 7)) * 8)] = v;
      }
    }
#pragma unroll
    for (int l = 0; l < 8; ++l) {              // B: 2048 16B chunks
      int i = l * 256 + tid;
      int nn = i >> 3, cc = i & 7;
      uint4 v = *(const uint4*)(Wtq + (size_t)nn * 256 + k0 + cc * 8);
      *(uint4*)&Bs_[nn * 64 + ((cc ^ (nn & 7)) * 8)] = v;
    }
    __syncthreads();
#pragma unroll
    for (int kk = 0; kk < 2; ++kk) {
      const int offk = (((kk << 2) | ql) ^ l7) * 8;
      bf16x8 bfr[4];
#pragma unroll
      for (int ni = 0; ni < 4; ++ni)
        bfr[ni] = *(const bf16x8*)&Bs_[(w * 64 + ni * 16 + cl) * 64 + offk];
#pragma unroll
      for (int mi = 0; mi < 5; ++mi) {
        bf16x8 afr = *(const bf16x8*)&As_[(mi * 16 + cl) * 64 + offk];
#pragma unroll
        for (int ni = 0; ni < 4; ++ni)
          acc[mi][ni] = __builtin_amdgcn_mfma_f32_16x16x32_bf16(afr, bfr[ni], acc[mi][ni], 0, 0, 0);
      }
    }
  }
  __syncthreads();                             // staging reads done; reuse smem as qlds
#pragma unroll
  for (int mi = 0; mi < 5; ++mi)
#pragma unroll
    for (int ni = 0; ni < 4; ++ni)
#pragma unroll
      for (int rr = 0; rr < 4; ++rr)
        qlds[(mi * 64 + 16 * ql + 4 * rr + w) * 72 + ni * 16 + cl] = f2bf(acc[mi][ni][rr]);
  __syncthreads();

#pragma unroll
  for (int t = 0; t < 5; ++t) {
    f32x4 sacc[4];
#pragma unroll
    for (int si = 0; si < 4; ++si) {
      bf16x8 a0 = *(const bf16x8*)&qlds[(t * 64 + si * 16 + cl) * 72 + ql * 8];
      bf16x8 a1 = *(const bf16x8*)&qlds[(t * 64 + si * 16 + cl) * 72 + ql * 8 + 32];
      f32x4 z = (f32x4){0.f, 0.f, 0.f, 0.f};
      z = __builtin_amdgcn_mfma_f32_16x16x32_bf16(a0, kfr0, z, 0, 0, 0);
      z = __builtin_amdgcn_mfma_f32_16x16x32_bf16(a1, kfr1, z, 0, 0, 0);
      sacc[si] = z;
    }
    const float* pp = prior + t * 4096;
    float colsum = 0.f;
#pragma unroll
    for (int si = 0; si < 4; ++si) {
#pragma unroll
      for (int r = 0; r < 4; ++r) {
        int s = si * 16 + ql * 4 + r;
        float sg = 1.f / (1.f + __expf(-sacc[si][r] * 0.125f));
        colsum += sg * pp[s * 64 + c];
      }
    }
    colsum += __shfl_xor(colsum, 16);
    colsum += __shfl_xor(colsum, 32);
    if (ql == 0)
      ssum[(size_t)n * 320 + t * 64 + c] = colsum - bps[((size_t)nb * 5 + t) * 64 + c];
  }
}

// ---------------- fused v-GEMM + o-GEMM (fully LDS-staged) ------------------------
__global__ __launch_bounds__(512, 2) void vo_gemm(const ushort_t* __restrict__ xb,
                                                  const ushort_t* __restrict__ Wtv,
                                                  const ushort_t* __restrict__ Wto,
                                                  const float* __restrict__ ssum,
                                                  ushort_t* __restrict__ ob,
                                                  float* __restrict__ ravg,
                                                  float* __restrict__ rmax) {
  __shared__ __align__(16) ushort_t As_[64 * 64];      // 8K
  __shared__ __align__(16) ushort_t Bs_[256 * 64];     // 32K
  __shared__ __align__(16) ushort_t Vs_[64 * 256];     // 32K
  __shared__ float redS[8], redM[8];
  const int tid = threadIdx.x;
  const int lane = tid & 63;
  const int w = tid >> 6, wr = w >> 2, wc = w & 3;
  const int g = blockIdx.x;                            // bt group, 1280 total
  const int row0 = g * 64;
  const int cl = lane & 15, ql = lane >> 4, l7 = lane & 7;

  f32x4 acc[2][4];
#pragma unroll
  for (int mi = 0; mi < 2; ++mi)
#pragma unroll
    for (int ni = 0; ni < 4; ++ni) acc[mi][ni] = (f32x4){0.f, 0.f, 0.f, 0.f};

  // ---- phase 1: V = xb @ Wv^T ----
  for (int t = 0; t < 4; ++t) {
    const int k0 = t * 64;
    if (t) __syncthreads();
    {                                          // A: 512 chunks, 1/thread
      int i = tid;
      int r = i >> 3, cpos = i & 7, csrc = cpos ^ (r & 7);
      gload16(xb + (size_t)(row0 + r) * 256 + k0 + csrc * 8, &As_[(w * 64) * 8]);
    }
#pragma unroll
    for (int l = 0; l < 4; ++l) {              // B: 2048 chunks
      int i = l * 512 + tid;
      int n = i >> 3, cpos = i & 7, csrc = cpos ^ (n & 7);
      gload16(Wtv + (size_t)n * 256 + k0 + csrc * 8, &Bs_[(l * 512 + w * 64) * 8]);
    }
    __syncthreads();
#pragma unroll
    for (int kk = 0; kk < 2; ++kk) {
      const int offk = (((kk << 2) | ql) ^ l7) * 8;
      bf16x8 bfr[4], afr[2];
#pragma unroll
      for (int ni = 0; ni < 4; ++ni)
        bfr[ni] = *(const bf16x8*)&Bs_[(wc * 64 + ni * 16 + cl) * 64 + offk];
#pragma unroll
      for (int mi = 0; mi < 2; ++mi)
        afr[mi] = *(const bf16x8*)&As_[(wr * 32 + mi * 16 + cl) * 64 + offk];
#pragma unroll
      for (int mi = 0; mi < 2; ++mi)
#pragma unroll
        for (int ni = 0; ni < 4; ++ni)
          acc[mi][ni] = __builtin_amdgcn_mfma_f32_16x16x32_bf16(afr[mi], bfr[ni], acc[mi][ni], 0, 0, 0);
    }
  }
  // scale + write Vs (chunk-XOR swizzled)
#pragma unroll
  for (int mi = 0; mi < 2; ++mi) {
    float sc[4];
#pragma unroll
    for (int r = 0; r < 4; ++r)
      sc[r] = ssum[(size_t)(row0 + wr * 32 + mi * 16 + ql * 4 + r) * 4 + wc];
#pragma unroll
    for (int ni = 0; ni < 4; ++ni) {
      int col = wc * 64 + ni * 16 + cl;
#pragma unroll
      for (int r = 0; r < 4; ++r) {
        int row = wr * 32 + mi * 16 + ql * 4 + r;
        int ch = (col >> 3) ^ (row & 31);
        Vs_[row * 256 + ch * 8 + (col & 7)] = f2bf(acc[mi][ni][r] * sc[r]);
      }
    }
  }
  __syncthreads();                             // Vs visible; phase-1 Bs reads done

  // ---- phase 2: O = Vs @ Wo^T ----
#pragma unroll
  for (int mi = 0; mi < 2; ++mi)
#pragma unroll
    for (int ni = 0; ni < 4; ++ni) acc[mi][ni] = (f32x4){0.f, 0.f, 0.f, 0.f};
  for (int t = 0; t < 4; ++t) {
    const int k0 = t * 64;
    if (t) __syncthreads();
#pragma unroll
    for (int l = 0; l < 4; ++l) {              // B: 2048 chunks (Wo)
      int i = l * 512 + tid;
      int n = i >> 3, cpos = i & 7, csrc = cpos ^ (n & 7);
      gload16(Wto + (size_t)n * 256 + k0 + csrc * 8, &Bs_[(l * 512 + w * 64) * 8]);
    }
    __syncthreads();
#pragma unroll
    for (int kk = 0; kk < 2; ++kk) {
      const int offk = (((kk << 2) | ql) ^ l7) * 8;
      const int ch = t * 8 + kk * 4 + ql;      // global k-chunk for Vs read
      bf16x8 bfr[4], afr[2];
#pragma unroll
      for (int ni = 0; ni < 4; ++ni)
        bfr[ni] = *(const bf16x8*)&Bs_[(wc * 64 + ni * 16 + cl) * 64 + offk];
#pragma unroll
      for (int mi = 0; mi < 2; ++mi) {
        int row = wr * 32 + mi * 16 + cl;
        afr[mi] = *(const bf16x8*)&Vs_[row * 256 + (ch ^ (row & 31)) * 8];
      }
#pragma unroll
      for (int mi = 0; mi < 2; ++mi)
#pragma unroll
        for (int ni = 0; ni < 4; ++ni)
          acc[mi][ni] = __builtin_amdgcn_mfma_f32_16x16x32_bf16(afr[mi], bfr[ni], acc[mi][ni], 0, 0, 0);
    }
  }
  // epilogue: write ob bf16 + SE avg/max over this block's bt group
  float lsum = 0.f, lmax = -3.4e38f;
#pragma unroll
  for (int mi = 0; mi < 2; ++mi)
#pragma unroll
    for (int ni = 0; ni < 4; ++ni) {
      int col = wc * 64 + ni * 16 + cl;
#pragma unroll
      for (int r = 0; r < 4; ++r) {
        int row = row0 + wr * 32 + mi * 16 + ql * 4 + r;
        float f = acc[mi][ni][r];
        ob[(size_t)row * 256 + col] = f2bf(f);
        lsum += f; lmax = fmaxf(lmax, f);
      }
    }
#pragma unroll
  for (int off = 32; off; off >>= 1) {
    lsum += __shfl_xor(lsum, off);
    lmax = fmaxf(lmax, __shfl_xor(lmax, off));
  }
  if (lane == 0) { redS[w] = lsum; redM[w] = lmax; }
  __syncthreads();
  if (tid == 0) {
    float s = 0.f, m = -3.4e38f;
#pragma unroll
    for (int i = 0; i < 8; ++i) { s += redS[i]; m = fmaxf(m, redM[i]); }
    ravg[g] = s * (1.f / 16384.f);
    rmax[g] = m;
  }
}

// ---------------- final: out = bf16(o)*se[b,t] + bf16(x), se computed inline ------
// out is write-only (never re-read): non-temporal stores keep L2 for ob/xb reads.
__global__ __launch_bounds__(256) void final_kernel(
    const ushort_t* __restrict__ xb, const ushort_t* __restrict__ ob,
    const float* __restrict__ ravg, const float* __restrict__ rmax,
    const float* __restrict__ fc1w, const float* __restrict__ fc1b,
    const float* __restrict__ fc2w, const float* __restrict__ fc2b,
    const float* __restrict__ bili, float* __restrict__ out) {
  __shared__ float sse;
  int i = blockIdx.x * 256 + threadIdx.x;      // float4 id, 5242880
  size_t j = (size_t)i * 4;
  int bt = (int)(j >> 14);
  uint2 uo = *(const uint2*)(ob + j);          // issue loads before serial SE
  uint2 ux = *(const uint2*)(xb + j);
  if (threadIdx.x == 0) {
    int b = bt / 5, t = bt % 5;
    float avg[5], mx[5];
    for (int tt = 0; tt < 5; ++tt) { avg[tt] = ravg[b * 5 + tt]; mx[tt] = rmax[b * 5 + tt]; }
    float w = bili[0];
    float s12[2];
    for (int p = 0; p < 2; ++p) {
      const float* in = p == 0 ? avg : mx;
      float a = fc2b[t];
      for (int jj = 0; jj < 25; ++jj) {
        float hh = fc1b[jj];
        for (int tt = 0; tt < 5; ++tt) hh += in[tt] * fc1w[tt * 25 + jj];
        a += fmaxf(hh, 0.f) * fc2w[jj * 5 + t];
      }
      s12[p] = 1.f / (1.f + __expf(-a));
    }
    sse = (1.f - w) * s12[0] + w * s12[1];
  }
  __syncthreads();
  float s = sse;
  f32x4 r = {bflo(uo.x) * s + bflo(ux.x), bfhi(uo.x) * s + bfhi(ux.x),
             bflo(uo.y) * s + bflo(ux.y), bfhi(uo.y) * s + bfhi(ux.y)};
  __builtin_nontemporal_store(r, (f32x4*)(out + j));
}

extern "C" void kernel_launch(void* const* d_in, const int* in_sizes, int n_in,
                              void* d_out, int out_size, void* d_ws, size_t ws_size,
                              hipStream_t stream) {
  const float* x     = (const float*)d_in[0];
  const float* bias  = (const float*)d_in[1];
  const float* Wq    = (const float*)d_in[2];
  const float* Wv    = (const float*)d_in[3];
  const float* Wo    = (const float*)d_in[4];
  const float* u_t   = (const float*)d_in[5];
  const float* dis   = (const float*)d_in[6];
  const float* sigma = (const float*)d_in[7];
  const float* fc1w  = (const float*)d_in[8];
  const float* fc1b  = (const float*)d_in[9];
  const float* fc2w  = (const float*)d_in[10];
  const float* fc2b  = (const float*)d_in[11];
  const float* bili  = (const float*)d_in[12];
  float* out = (float*)d_out;

  // workspace layout (bytes), ~94.5 MB. qvb holds o only (v never touches HBM).
  char* wsb = (char*)d_ws;
  ushort_t* xbuf = (ushort_t*)wsb;             wsb += 41943040;  // bf16(x), alive to end
  ushort_t* qvb  = (ushort_t*)wsb;             wsb += 41943040;  // o bf16
  ushort_t* kb   = (ushort_t*)wsb;             wsb += 8388608;   // k bf16 [B,S,F]
  ushort_t* Wt   = (ushort_t*)wsb;             wsb += 393216;    // 3 x W^T bf16
  float*    ssum = (float*)wsb;                wsb += 1310720;
  float*    prior= (float*)wsb;                wsb += 81920;
  float*    bps  = (float*)wsb;                wsb += 327680;
  float*    ravg = (float*)wsb;                wsb += 5120;
  float*    rmax = (float*)wsb;                wsb += 5120;

  // 1) fused prep: Wt | prior | bps | (k, xb)
  prep_kernel<<<4176, 256, 0, stream>>>(x, u_t, Wq, Wv, Wo, dis, sigma, bias,
                                        Wt, prior, bps, kb, xbuf);
  // 2) fused q-GEMM + score (q never touches HBM)
  qscore<<<1024, 256, 0, stream>>>(xbuf, Wt, kb, prior, bps, ssum);
  // 3) fused v-GEMM + o-GEMM (v never touches HBM), SE avg/max in epilogue
  vo_gemm<<<1280, 512, 0, stream>>>(xbuf, Wt + 65536, Wt + 131072, ssum,
                                    qvb, ravg, rmax);
  // 4) final with inline SE MLP
  final_kernel<<<20480, 256, 0, stream>>>(xbuf, qvb, ravg, rmax,
                                          fc1w, fc1b, fc2w, fc2b, bili, out);
}